// Round 8
// baseline (230.023 us; speedup 1.0000x reference)
//
#include <hip/hip_runtime.h>

typedef __attribute__((ext_vector_type(4))) float f32x4;
typedef __attribute__((ext_vector_type(16))) float f32x16;
typedef __attribute__((ext_vector_type(4))) int i32x4;
typedef __attribute__((ext_vector_type(8))) int i32x8;
typedef union { i32x8 v8; i32x4 v4[2]; } opnd;

// e2m1 (MX-fp4) round-to-nearest (software fallback): values {0,.5,1,1.5,2,3,4,6}.
__device__ __forceinline__ unsigned fp4q(float v) {
  float a = __builtin_fabsf(v);
  unsigned q = (unsigned)(a > 0.25f) + (a > 0.75f) + (a > 1.25f) + (a > 1.75f)
             + (a > 2.5f) + (a > 3.5f) + (a > 5.0f);
  return q | (v < 0.0f ? 8u : 0u);
}

// PKFP4(old, x, y, sel): pack fp4(x) (lo nibble) and fp4(y) (hi nibble) into
// byte `sel` of `old`. HW path uses gfx950 v_cvt_scalef32_pk_fp4_f32.
#if __has_builtin(__builtin_amdgcn_cvt_scalef32_pk_fp4_f32)
#define PKFP4(old, x, y, s) __builtin_amdgcn_cvt_scalef32_pk_fp4_f32((old), (x), (y), 1.0f, (s))
#else
#define PKFP4(old, x, y, s) ((old) | ((fp4q(x) | (fp4q(y) << 4)) << (8 * (s))))
#endif

// fp8-tiled frag-linear layout: 32r x 64k blocks of 2048B.
__device__ __forceinline__ long tiled_addr(long r, long k, int nkb) {
  return (((r >> 5) * nkb) + (k >> 6)) * 2048 + ((k & 16) ? 1024 : 0)
       + (((r & 31) + (((k >> 5) & 1) << 5)) << 4) + (k & 15);
}
// fp4-tiled frag-linear layout: 32r x 64k blocks of 1024B.
__device__ __forceinline__ long tile4_addr(long r, long k, int nkb) {
  return (((r >> 5) * nkb) + (k >> 6)) * 1024
       + (((r & 31) + (((k >> 5) & 1) << 5)) << 4) + ((k & 31) >> 1);
}

// L2-supertile block remap (r13: cuts FETCH, no time cost).
__device__ __forceinline__ long remap_wg(int lin, int nwg, int gx) {
  long g = lin;
  if ((nwg & 7) == 0) {
    int cpx = nwg >> 3;
    int gyx = cpx / gx;
    int xcd = lin & 7, idx = lin >> 3;
    if ((gx & 3) == 0 && gyx >= 4 && (gyx & 3) == 0) {
      int st = idx >> 4, wi = idx & 15;
      int nstr = gx >> 2;
      int str = st % nstr, stc = st / nstr;
      int r = str * 4 + (wi & 3);
      int c2 = stc * 4 + (wi >> 2);
      g = (long)xcd * cpx + (long)c2 * gx + r;
    } else {
      g = (long)xcd * cpx + idx;
    }
  }
  return g;
}

// ---------- fp32 -> fp4 e2m1 (x4096*6) for adj, fp4-tiled layout ----------
__global__ __launch_bounds__(256) void cvtAdj4t(const float* __restrict__ in,
                                                unsigned char* __restrict__ out, long n) {
  long i = ((long)blockIdx.x * 256 + threadIdx.x) * 8;
  if (i >= n) return;
  float4 a = *(const float4*)(in + i);
  float4 b = *(const float4*)(in + i + 4);
  const float S = 24576.0f;                  // 4096 * 6
  unsigned word = PKFP4(0u, a.x * S, a.y * S, 0);
  word = PKFP4(word, a.z * S, a.w * S, 1);
  word = PKFP4(word, b.x * S, b.y * S, 2);
  word = PKFP4(word, b.z * S, b.w * S, 3);
  long r = i >> 12;                 // row (K = 4096)
  long k = i & 4095;
  *(int*)(out + tile4_addr(r, k, 64)) = (int)word;
}

// ---------- x fp32 -> fp4-tiled x4T (transpose): row = bl*128 + w, k = m ----------
__global__ __launch_bounds__(256) void cvtX4t(const float* __restrict__ X,
                                              unsigned char* __restrict__ out4) {
  __shared__ float tile[32][33];
  const int tid = threadIdx.x;
  const long bl = blockIdx.z;
  const int m0 = blockIdx.y * 32;
  const int w0 = blockIdx.x * 32;
  const float* xb = X + (bl * 4096 + m0) * 128 + w0;
  int row = tid >> 3, cg = tid & 7;
  float4 v = *(const float4*)(xb + (long)row * 128 + cg * 4);
  tile[row][cg * 4 + 0] = v.x;
  tile[row][cg * 4 + 1] = v.y;
  tile[row][cg * 4 + 2] = v.z;
  tile[row][cg * 4 + 3] = v.w;
  __syncthreads();
  if (tid < 128) {
    int wv = tid & 31, mg = tid >> 5;          // out row wv, 8 m's per thread
    float t[8];
#pragma unroll
    for (int i = 0; i < 8; ++i) t[i] = tile[mg * 8 + i][wv];
    unsigned word = PKFP4(0u, t[0], t[1], 0);
    word = PKFP4(word, t[2], t[3], 1);
    word = PKFP4(word, t[4], t[5], 2);
    word = PKFP4(word, t[6], t[7], 3);
    long r = bl * 128 + w0 + wv;
    long k = m0 + mg * 8;
    *(int*)(out4 + tile4_addr(r, k, 64)) = (int)word;
  }
}

// -------- W1T8 = fp8-tiled (W1*16) [256f][128w]; W2T8 = fp8-tiled (W2*16) [128cc][256f] --------
__global__ __launch_bounds__(256) void prep_params(const float* __restrict__ W1,
                                                   const float* __restrict__ W2,
                                                   unsigned char* __restrict__ W1T8,
                                                   unsigned char* __restrict__ W2T8) {
  int idx = blockIdx.x * 256 + threadIdx.x;          // 0..65535
  if (idx < 32768) {
    int f = idx >> 7, wv = idx & 127;
    float v = W1[wv * 256 + f] * 16.0f;              // W1 is [128w][256f]
    int pk = __builtin_amdgcn_cvt_pk_fp8_f32(v, v, 0, 0);
    W1T8[tiled_addr(f, wv, 2)] = (unsigned char)(pk & 0xff);
  } else {
    int t = idx - 32768;
    int cc = t >> 8, f = t & 255;
    float v = W2[f * 128 + cc] * 16.0f;              // W2 is [256f][128c]
    int pk = __builtin_amdgcn_cvt_pk_fp8_f32(v, v, 0, 0);
    W2T8[tiled_addr(cc, f, 4)] = (unsigned char)(pk & 0xff);
  }
}

// ------- gemmS1 v7: hybrid operand sourcing (r7 model: LDS-read was the top
// pipe at 576 cyc/kt/CU because the 2x2 wave grid reads every staged frag
// twice). adj now DIRECT global->reg (3-set dist-2 rotation; 2x duplication
// absorbed by L1), x stays LDS-staged (4-slot x 4KB ring = 16KB, aliases the
// epilogue's S1buf). Per-kt bodies, counted vmcnt: steady 6 (forces A(kt) and
// transitively S(kt+1)); ramp 5; tail 5/2/0. New balance: matrix 427 (top),
// VMEM ~375, LDS ~282 cyc/kt/CU. Epilogue byte-identical to r3/r7. -------
__global__ __launch_bounds__(256, 3) void gemmS1(const unsigned char* __restrict__ A4,
                                                 const unsigned char* __restrict__ X4,
                                                 const unsigned char* __restrict__ W1T8,
                                                 const unsigned char* __restrict__ W2T8,
                                                 unsigned char* __restrict__ t2T4,
                                                 const float* __restrict__ b1,
                                                 int K, int gx) {
  __shared__ unsigned char lds[49152];         // x-ring 4x4KB; later S1buf[16K]+hbuf[32K]
  const int tid = threadIdx.x;
  const int l = tid & 63;
  const int w = tid >> 6;                      // 0..3
  long g = remap_wg(blockIdx.x, gridDim.x, gx);   // gx = 32
  const long row0 = (g % gx) * 128;
  const long bl = g / gx;
  const int nkb = K >> 6;
  const int wr = w >> 1, wc = w & 1;
  // x staging: wave w stages x frag w (1 gload_lds per kt); slot = 4KB.
  const unsigned char* sXp = X4 + ((bl * 4 + w) * (long)nkb) * 1024 + l * 16;
  unsigned char* ldsw = lds + w * 1024;        // + slot*4096
  const unsigned char* rX = lds + (wc * 2) * 1024 + l * 16;   // + slot*4096, +j*1024
  // adj direct: wave loads frags (row0/32 + wr*2 + fi), kt-block at +kt*1024.
  const unsigned char* pA = A4 + (((row0 >> 5) + wr * 2) * (long)nkb) * 1024 + l * 16;

  f32x16 acc[2][2] = {};
  opnd xv[2], a0[2], a1[2], a2[2];             // x frags; 3 adj sets (dist-2)
  const i32x4 z4 = {0, 0, 0, 0};
  xv[0].v4[1] = z4; xv[1].v4[1] = z4;
#pragma unroll
  for (int fi = 0; fi < 2; ++fi) { a0[fi].v4[1] = z4; a1[fi].v4[1] = z4; a2[fi].v4[1] = z4; }

#define STGX(KT, SL) __builtin_amdgcn_global_load_lds(                                \
    (const unsigned int*)(const void*)(sXp + (long)(KT) * 1024),                      \
    (unsigned int*)(ldsw + (SL) * 4096), 16, 0, 0)
#define LOADA(KT, AV) do { long o_ = (long)(KT) * 1024;                               \
    AV[0].v4[0] = *(const i32x4*)(pA + o_);                                           \
    AV[1].v4[0] = *(const i32x4*)(pA + (long)nkb * 1024 + o_); } while (0)
#define LDX(SL) do { const unsigned char* p_ = rX + (SL) * 4096;                      \
    xv[0].v4[0] = *(const i32x4*)(p_);                                                \
    xv[1].v4[0] = *(const i32x4*)(p_ + 1024); } while (0)
  // Swapped roles: srcA = x-frag, srcB = adj-frag -> acc lanes = n, regs = w.
  // scale_b = 124 (2^-3) folds the S1' /8. 4 MFMAs per wave per kt.
#define MFMAS(AV) do {                                                                \
    __builtin_amdgcn_s_setprio(1);                                                    \
    _Pragma("unroll") for (int fi = 0; fi < 2; ++fi)                                  \
      _Pragma("unroll") for (int j = 0; j < 2; ++j)                                   \
        acc[fi][j] = __builtin_amdgcn_mfma_scale_f32_32x32x64_f8f6f4(                 \
            xv[j].v8, AV[fi].v8, acc[fi][j], 4, 4, 0, 127, 0, 124);                   \
    __builtin_amdgcn_s_setprio(0); } while (0)
  // Body KT: ds-read slot SLR(=KT&3); stage S(KT+3)->slot SLS; load A(KT+2)->ALD;
  // vmcnt(N) forces A(KT) + S(KT+1); 4 MFMA on AUSE(=a[KT%3]); barrier.
#define BODY(KT, SLR, SLS, AUSE, ALD, N, DOSTG, DOA) do {                             \
    LDX(SLR);                                                                         \
    if (DOSTG) STGX((KT) + 3, SLS);                                                   \
    if (DOA) LOADA((KT) + 2, ALD);                                                    \
    asm volatile("s_waitcnt vmcnt(" N ")" ::: "memory");                              \
    MFMAS(AUSE);                                                                      \
    __builtin_amdgcn_s_barrier(); } while (0)

  // nkt = 64 per-kt bodies. Stage ring slots = kt&3; adj set = kt%3.
  STGX(0, 0); STGX(1, 1); STGX(2, 2);
  LOADA(0, a0); LOADA(1, a1);
  asm volatile("s_waitcnt vmcnt(6)" ::: "memory");   // force S(0) complete
  __builtin_amdgcn_s_barrier();

  BODY(0, 0, 3, a0, a2, "5", 1, 1);
  for (int b = 1; b <= 49; b += 12) {          // bodies 1..60 (5 x 12)
    BODY(b + 0,  1, 0, a1, a0, "6", 1, 1);
    BODY(b + 1,  2, 1, a2, a1, "6", 1, 1);
    BODY(b + 2,  3, 2, a0, a2, "6", 1, 1);
    BODY(b + 3,  0, 3, a1, a0, "6", 1, 1);
    BODY(b + 4,  1, 0, a2, a1, "6", 1, 1);
    BODY(b + 5,  2, 1, a0, a2, "6", 1, 1);
    BODY(b + 6,  3, 2, a1, a0, "6", 1, 1);
    BODY(b + 7,  0, 3, a2, a1, "6", 1, 1);
    BODY(b + 8,  1, 0, a0, a2, "6", 1, 1);
    BODY(b + 9,  2, 1, a1, a0, "6", 1, 1);
    BODY(b + 10, 3, 2, a2, a1, "6", 1, 1);
    BODY(b + 11, 0, 3, a0, a2, "6", 1, 1);
  }
  BODY(61, 1, 0, a1, a0, "5", 0, 1);           // loads A(63) -> a0
  BODY(62, 2, 0, a2, a0, "2", 0, 0);
  BODY(63, 3, 0, a0, a0, "0", 0, 0);
#undef STGX
#undef LOADA
#undef LDX
#undef MFMAS
#undef BODY

  unsigned char* S1buf = lds;                  // 16KB, aliases ring (dead now)
  unsigned char* hbuf = lds + 16384;           // 32KB

  // S1' = fp8(acc) -> S1buf (acc already carries the 2^-3 scale).
  const int hi = l >> 5;
  const int ln = l & 31;
#pragma unroll
  for (int fi = 0; fi < 2; ++fi) {
    int n = (wr * 2 + fi) * 32 + ln;
#pragma unroll
    for (int j = 0; j < 2; ++j) {
      int wb = (wc * 2 + j) * 32 + 4 * hi;
#pragma unroll
      for (int r4 = 0; r4 < 4; ++r4) {
        int w0 = wb + 8 * r4;
        int word = __builtin_amdgcn_cvt_pk_fp8_f32(acc[fi][j][4 * r4 + 0],
                                                   acc[fi][j][4 * r4 + 1], 0, false);
        word = __builtin_amdgcn_cvt_pk_fp8_f32(acc[fi][j][4 * r4 + 2],
                                               acc[fi][j][4 * r4 + 3], word, true);
        *(int*)(S1buf + tiled_addr(n, w0, 2)) = word;
      }
    }
  }
  __syncthreads();                             // acc dead; regs reused below

  // mini1 (swapped): acc = W1frag @ S1frag -> lanes = n, regs = f.
  const float c1 = 128.0f / 49152.0f;
#pragma unroll
  for (int hh = 0; hh < 2; ++hh) {
#pragma unroll
    for (int fi = 0; fi < 2; ++fi)
#pragma unroll
      for (int jb = 0; jb < 2; ++jb) acc[fi][jb] = (f32x16){};
#pragma unroll
    for (int kt1 = 0; kt1 < 2; ++kt1) {
#pragma unroll
      for (int jb = 0; jb < 2; ++jb) {
        opnd aw;
        const unsigned char* pW = W1T8 + (long)((hh * 4 + wc * 2 + jb) * 2 + kt1) * 2048 + l * 16;
        aw.v4[0] = *(const i32x4*)(pW);
        aw.v4[1] = *(const i32x4*)(pW + 1024);
#pragma unroll
        for (int fi = 0; fi < 2; ++fi) {
          opnd bs;
          const unsigned char* pS = S1buf + (long)((wr * 2 + fi) * 2 + kt1) * 2048 + l * 16;
          bs.v4[0] = *(const i32x4*)(pS);
          bs.v4[1] = *(const i32x4*)(pS + 1024);
          acc[fi][jb] = __builtin_amdgcn_mfma_scale_f32_32x32x64_f8f6f4(
              aw.v8, bs.v8, acc[fi][jb], 0, 0, 0, 127, 0, 127);
        }
      }
    }
#pragma unroll
    for (int jb = 0; jb < 2; ++jb) {
      int fb = (hh * 4 + wc * 2 + jb) * 32 + 4 * hi;
#pragma unroll
      for (int r4 = 0; r4 < 4; ++r4) {
        int f0 = fb + 8 * r4;
        float4 bb = *(const float4*)(b1 + f0);
#pragma unroll
        for (int fi = 0; fi < 2; ++fi) {
          int n = (wr * 2 + fi) * 32 + ln;
          float v0 = fmaxf(fmaf(acc[fi][jb][4 * r4 + 0], c1, bb.x * 128.0f), 0.0f);
          float v1 = fmaxf(fmaf(acc[fi][jb][4 * r4 + 1], c1, bb.y * 128.0f), 0.0f);
          float v2 = fmaxf(fmaf(acc[fi][jb][4 * r4 + 2], c1, bb.z * 128.0f), 0.0f);
          float v3 = fmaxf(fmaf(acc[fi][jb][4 * r4 + 3], c1, bb.w * 128.0f), 0.0f);
          int word = __builtin_amdgcn_cvt_pk_fp8_f32(v0, v1, 0, false);
          word = __builtin_amdgcn_cvt_pk_fp8_f32(v2, v3, word, true);
          *(int*)(hbuf + tiled_addr(n, f0, 4)) = word;
        }
      }
    }
  }
  __syncthreads();                             // hbuf complete

  // mini2 (unswapped; lane = cc matches t2T4 store): acc = h' @ W2T8^T over 256 f.
#pragma unroll
  for (int fi = 0; fi < 2; ++fi)
#pragma unroll
    for (int jb = 0; jb < 2; ++jb) acc[fi][jb] = (f32x16){};
#pragma unroll
  for (int kt2 = 0; kt2 < 4; ++kt2) {
#pragma unroll
    for (int jb = 0; jb < 2; ++jb) {
      opnd bw;
      const unsigned char* pW = W2T8 + (long)((wc * 2 + jb) * 4 + kt2) * 2048 + l * 16;
      bw.v4[0] = *(const i32x4*)(pW);
      bw.v4[1] = *(const i32x4*)(pW + 1024);
#pragma unroll
      for (int fi = 0; fi < 2; ++fi) {
        opnd ah;
        const unsigned char* pH = hbuf + (long)((wr * 2 + fi) * 4 + kt2) * 2048 + l * 16;
        ah.v4[0] = *(const i32x4*)(pH);
        ah.v4[1] = *(const i32x4*)(pH + 1024);
        acc[fi][jb] = __builtin_amdgcn_mfma_scale_f32_32x32x64_f8f6f4(
            ah.v8, bw.v8, acc[fi][jb], 0, 0, 0, 127, 0, 127);
      }
    }
  }
  unsigned char* ob = t2T4 + bl * 262144;
#pragma unroll
  for (int fi = 0; fi < 2; ++fi) {
#pragma unroll
    for (int jb = 0; jb < 2; ++jb) {
      int cc = wc * 64 + jb * 32 + ln;
#pragma unroll
      for (int run = 0; run < 4; ++run) {
        long n0 = row0 + wr * 64 + fi * 32 + 8 * run + 4 * hi;
        const float s = 0.125f;                // 256 / 2048
        unsigned pkw = PKFP4(0u, acc[fi][jb][run * 4 + 0] * s,
                                 acc[fi][jb][run * 4 + 1] * s, 0);
        pkw = PKFP4(pkw, acc[fi][jb][run * 4 + 2] * s,
                         acc[fi][jb][run * 4 + 3] * s, 1);
        *(ushort*)(ob + tile4_addr(cc, n0, 64)) = (ushort)pkw;
      }
    }
  }
}

// ------- G4+lsm v2 (r3-proven, best-total config): 8-wave MX-fp4 GEMM, fused
// log_softmax. Ring 8 slots x 8KB (64KB LDS), A direct prefetch dist-3 (4 reg
// sets), B staged 6 ahead; steady-state vmcnt(10); 8r x 8c per-XCD remap. -------
__global__ __launch_bounds__(512) void gemm256sm(const unsigned char* __restrict__ A4,
                                                 const unsigned char* __restrict__ B4,
                                                 float* __restrict__ out,
                                                 const float* __restrict__ bias,
                                                 float ooScale, int K, int gx,
                                                 int chunkBase) {
  __shared__ unsigned char ring[65536];        // 8 slots x 8KB (B stage)
  const int tid = threadIdx.x;
  const int l = tid & 63;
  const int w = tid >> 6;
  int lin = blockIdx.x;
  const int nwg = gridDim.x;
  if (gx == 16 && (nwg & 63) == 0) {
    // 8r x (nwg/64)c per XCD: halves the per-XCD adj footprint vs plain swizzle.
    int xcd = lin & 7, idx = lin >> 3;
    int cpg = nwg >> 6;
    int r = ((xcd & 1) << 3) + (idx & 7);
    int c = (xcd >> 1) * cpg + (idx >> 3);
    lin = c * gx + r;
  } else if ((nwg & 7) == 0) {
    int cpx = nwg >> 3;
    lin = (lin & 7) * cpx + (lin >> 3);
  }
  const long row0 = (long)(lin % gx) * 256;
  const long col0 = (long)(lin / gx) * 256;
  const int nkb = K >> 6;
  const unsigned char* sBp = B4 + (((col0 >> 5) + w) * (long)nkb) * 1024 + l * 16;
  unsigned char* ringw = ring + w * 1024;
  const unsigned char* ringr = ring + ((w & 1) * 4) * 1024 + l * 16;
  const unsigned char* pA = A4 + (((row0 + (w >> 1) * 64) >> 5) * (long)nkb) * 1024 + l * 16;

  f32x16 acc[2][4] = {};
  opnd bv[4], a0v[2], a1v[2], a2v[2], a3v[2];
  const i32x4 z4 = {0, 0, 0, 0};
#pragma unroll
  for (int j = 0; j < 4; ++j) bv[j].v4[1] = z4;
#pragma unroll
  for (int fi = 0; fi < 2; ++fi) {
    a0v[fi].v4[1] = z4; a1v[fi].v4[1] = z4; a2v[fi].v4[1] = z4; a3v[fi].v4[1] = z4;
  }

#define STGB(KT) __builtin_amdgcn_global_load_lds(                                    \
    (const unsigned int*)(const void*)(sBp + (long)(KT) * 1024),                      \
    (unsigned int*)(ringw + (((KT) & 7) << 13)), 16, 0, 0)
#define LOADA(KT, AV) do { long o_ = (long)(KT) * 1024;                               \
    AV[0].v4[0] = *(const i32x4*)(pA + o_);                                           \
    AV[1].v4[0] = *(const i32x4*)(pA + (long)nkb * 1024 + o_); } while (0)
#define LDB(KT) do { const unsigned char* p_ = ringr + (((KT) & 7) << 13);            \
    bv[0].v4[0] = *(const i32x4*)(p_);                                                \
    bv[1].v4[0] = *(const i32x4*)(p_ + 1024);                                         \
    bv[2].v4[0] = *(const i32x4*)(p_ + 2048);                                         \
    bv[3].v4[0] = *(const i32x4*)(p_ + 3072); } while (0)
#define MFMAS(AV) do { __builtin_amdgcn_s_setprio(1);                                 \
    _Pragma("unroll") for (int fi = 0; fi < 2; ++fi)                                  \
      _Pragma("unroll") for (int j = 0; j < 4; ++j)                                   \
        acc[fi][j] = __builtin_amdgcn_mfma_scale_f32_32x32x64_f8f6f4(                 \
            AV[fi].v8, bv[j].v8, acc[fi][j], 4, 4, 0, 127, 0, 127);                   \
    __builtin_amdgcn_s_setprio(0); } while (0)
// Body KT: ds-read slot KT, issue A(KT+3), stage slot KT+6, wait, 8 MFMA, barrier.
#define BODY(KT, N, DOSTG, DOA, ALD, AUSE) do {                                       \
    LDB(KT);                                                                          \
    if (DOA) LOADA((KT) + 3, ALD);                                                    \
    if (DOSTG) STGB((KT) + 6);                                                        \
    asm volatile("s_waitcnt vmcnt(" N ")" ::: "memory");                              \
    MFMAS(AUSE);                                                                      \
    __builtin_amdgcn_s_barrier(); } while (0)

  const int nkt = K >> 6;                      // 64
  LOADA(0, a0v); LOADA(1, a1v); LOADA(2, a2v);
  STGB(0); STGB(1); STGB(2); STGB(3); STGB(4); STGB(5);
  asm volatile("s_waitcnt vmcnt(5)" ::: "memory");   // own S(0) done (A(0..2) older)
  __builtin_amdgcn_s_barrier();

  BODY(0, "7", 1, 1, a3v, a0v);
  BODY(1, "9", 1, 1, a0v, a1v);
  BODY(2, "11", 1, 1, a1v, a2v);
  for (int kt = 3; kt + 9 <= nkt - 1; kt += 4) {     // kt = 3..51, bodies 3..54
    BODY(kt,     "10", 1, 1, a2v, a3v);
    BODY(kt + 1, "10", 1, 1, a3v, a0v);
    BODY(kt + 2, "10", 1, 1, a0v, a1v);
    BODY(kt + 3, "10", 1, 1, a1v, a2v);
  }
  BODY(55, "10", 1, 1, a2v, a3v);
  BODY(56, "10", 1, 1, a3v, a0v);
  BODY(57, "10", 1, 1, a0v, a1v);                    // stages S(63), last
  BODY(58, "9",  0, 1, a1v, a2v);
  BODY(59, "8",  0, 1, a2v, a3v);
  BODY(60, "7",  0, 1, a3v, a0v);
  BODY(61, "4",  0, 0, a0v, a1v);
  BODY(62, "2",  0, 0, a0v, a2v);
  BODY(63, "0",  0, 0, a0v, a3v);
#undef STGB
#undef LOADA
#undef LDB
#undef MFMAS
#undef BODY

  const int hi = l >> 5;
  const int bl = (int)(col0 >> 7) + (w & 1);
  float bb[4];
#pragma unroll
  for (int j = 0; j < 4; ++j) bb[j] = bias[j * 32 + (l & 31)];
#pragma unroll
  for (int fi = 0; fi < 2; ++fi) {
#pragma unroll
    for (int rr = 0; rr < 16; ++rr) {
      float v0 = acc[fi][0][rr] * ooScale + bb[0];
      float v1 = acc[fi][1][rr] * ooScale + bb[1];
      float v2 = acc[fi][2][rr] * ooScale + bb[2];
      float v3 = acc[fi][3][rr] * ooScale + bb[3];
      float m = fmaxf(fmaxf(v0, v1), fmaxf(v2, v3));
#pragma unroll
      for (int o = 16; o > 0; o >>= 1) m = fmaxf(m, __shfl_xor(m, o));
      float s = __expf(v0 - m) + __expf(v1 - m) + __expf(v2 - m) + __expf(v3 - m);
#pragma unroll
      for (int o = 16; o > 0; o >>= 1) s += __shfl_xor(s, o);
      float lse = m + __logf(s);
      long row = row0 + (w >> 1) * 64 + fi * 32 + ((rr & 3) + 8 * (rr >> 2) + 4 * hi);
      float* dst = out + ((long)(chunkBase + bl) * 4096 + row) * 128;
      dst[(l & 31)] = v0 - lse;
      dst[32 + (l & 31)] = v1 - lse;
      dst[64 + (l & 31)] = v2 - lse;
      dst[96 + (l & 31)] = v3 - lse;
    }
  }
}

extern "C" void kernel_launch(void* const* d_in, const int* in_sizes, int n_in,
                              void* d_out, int out_size, void* d_ws, size_t ws_size,
                              hipStream_t stream) {
  const float* x = (const float*)d_in[0];    // [64][4096][128]
  const float* adj = (const float*)d_in[1];  // [4096][4096]
  const float* W1 = (const float*)d_in[2];   // [128][256]
  const float* b1 = (const float*)d_in[3];   // [256]
  const float* W2 = (const float*)d_in[4];   // [256][128]
  const float* b2 = (const float*)d_in[5];   // [128]
  float* out = (float*)d_out;
  char* ws = (char*)d_ws;

  unsigned char* adj4 = (unsigned char*)ws;                       // 8 MiB
  unsigned char* W1T8 = (unsigned char*)(ws + 8388608);           // 32 KiB
  unsigned char* W2T8 = (unsigned char*)(ws + 8388608 + 32768);   // 32 KiB
  const size_t base = 9ull * 1024 * 1024;

  // chunk c (even divisors of 64): need = base + 2 * c * 256KB (x4T + t2T4)
  const int cands[6] = {64, 32, 16, 8, 4, 2};
  int c = 2;
  for (int t = 0; t < 6; ++t) {
    size_t need = base + (size_t)cands[t] * 524288;
    if (need <= ws_size) { c = cands[t]; break; }
  }
  unsigned char* x4T = (unsigned char*)(ws + base);               // c * 256 KiB
  unsigned char* t2T4 = x4T + (size_t)c * 262144;                 // c * 256 KiB

  cvtAdj4t<<<8192, 256, 0, stream>>>(adj, adj4, (long)4096 * 4096);
  prep_params<<<256, 256, 0, stream>>>(W1, W2, W1T8, W2T8);

  int chunks = 64 / c;
  for (int cb = 0; cb < chunks; ++cb) {
    int base_bl = cb * c;
    const float* xc = x + (long)base_bl * 4096 * 128;

    // x -> fp4-tiled transpose (rows = bl*128 + w, k = m)
    cvtX4t<<<dim3(4, 128, c), 256, 0, stream>>>(xc, x4T);
    // gemmS1 v7: t2T4 = fp4(256 * (relu((adj@x)@W1 + b1) @ W2)), K = 4096
    gemmS1<<<32 * c, 256, 0, stream>>>(adj4, x4T, W1T8, W2T8, t2T4, b1, 4096, 32);
    // G4+lsm v2: out = log_softmax(adj@t2 + b2)
    gemm256sm<<<16 * (c / 2), 512, 0, stream>>>(adj4, t2T4, out, b2,
                                                1.0f / 6291456.0f, 4096, 16, base_bl);
  }
}

// Round 9
// 229.186 us; speedup vs baseline: 1.0037x; 1.0037x over previous
//
#include <hip/hip_runtime.h>

typedef __attribute__((ext_vector_type(4))) float f32x4;
typedef __attribute__((ext_vector_type(16))) float f32x16;
typedef __attribute__((ext_vector_type(4))) int i32x4;
typedef __attribute__((ext_vector_type(8))) int i32x8;
typedef union { i32x8 v8; i32x4 v4[2]; } opnd;

// e2m1 (MX-fp4) round-to-nearest (software fallback): values {0,.5,1,1.5,2,3,4,6}.
__device__ __forceinline__ unsigned fp4q(float v) {
  float a = __builtin_fabsf(v);
  unsigned q = (unsigned)(a > 0.25f) + (a > 0.75f) + (a > 1.25f) + (a > 1.75f)
             + (a > 2.5f) + (a > 3.5f) + (a > 5.0f);
  return q | (v < 0.0f ? 8u : 0u);
}

// PKFP4(old, x, y, sel): pack fp4(x) (lo nibble) and fp4(y) (hi nibble) into
// byte `sel` of `old`. HW path uses gfx950 v_cvt_scalef32_pk_fp4_f32.
#if __has_builtin(__builtin_amdgcn_cvt_scalef32_pk_fp4_f32)
#define PKFP4(old, x, y, s) __builtin_amdgcn_cvt_scalef32_pk_fp4_f32((old), (x), (y), 1.0f, (s))
#else
#define PKFP4(old, x, y, s) ((old) | ((fp4q(x) | (fp4q(y) << 4)) << (8 * (s))))
#endif

// fp8-tiled frag-linear layout: 32r x 64k blocks of 2048B.
__device__ __forceinline__ long tiled_addr(long r, long k, int nkb) {
  return (((r >> 5) * nkb) + (k >> 6)) * 2048 + ((k & 16) ? 1024 : 0)
       + (((r & 31) + (((k >> 5) & 1) << 5)) << 4) + (k & 15);
}
// fp4-tiled frag-linear layout: 32r x 64k blocks of 1024B.
__device__ __forceinline__ long tile4_addr(long r, long k, int nkb) {
  return (((r >> 5) * nkb) + (k >> 6)) * 1024
       + (((r & 31) + (((k >> 5) & 1) << 5)) << 4) + ((k & 31) >> 1);
}

// L2-supertile block remap (r13: cuts FETCH, no time cost).
__device__ __forceinline__ long remap_wg(int lin, int nwg, int gx) {
  long g = lin;
  if ((nwg & 7) == 0) {
    int cpx = nwg >> 3;
    int gyx = cpx / gx;
    int xcd = lin & 7, idx = lin >> 3;
    if ((gx & 3) == 0 && gyx >= 4 && (gyx & 3) == 0) {
      int st = idx >> 4, wi = idx & 15;
      int nstr = gx >> 2;
      int str = st % nstr, stc = st / nstr;
      int r = str * 4 + (wi & 3);
      int c2 = stc * 4 + (wi >> 2);
      g = (long)xcd * cpx + (long)c2 * gx + r;
    } else {
      g = (long)xcd * cpx + idx;
    }
  }
  return g;
}

// ---------- fp32 -> fp4 e2m1 (x4096*6) for adj, fp4-tiled layout ----------
__global__ __launch_bounds__(256) void cvtAdj4t(const float* __restrict__ in,
                                                unsigned char* __restrict__ out, long n) {
  long i = ((long)blockIdx.x * 256 + threadIdx.x) * 8;
  if (i >= n) return;
  float4 a = *(const float4*)(in + i);
  float4 b = *(const float4*)(in + i + 4);
  const float S = 24576.0f;                  // 4096 * 6
  unsigned word = PKFP4(0u, a.x * S, a.y * S, 0);
  word = PKFP4(word, a.z * S, a.w * S, 1);
  word = PKFP4(word, b.x * S, b.y * S, 2);
  word = PKFP4(word, b.z * S, b.w * S, 3);
  long r = i >> 12;                 // row (K = 4096)
  long k = i & 4095;
  *(int*)(out + tile4_addr(r, k, 64)) = (int)word;
}

// ---------- x fp32 -> fp4-tiled x4T (transpose): row = bl*128 + w, k = m ----------
__global__ __launch_bounds__(256) void cvtX4t(const float* __restrict__ X,
                                              unsigned char* __restrict__ out4) {
  __shared__ float tile[32][33];
  const int tid = threadIdx.x;
  const long bl = blockIdx.z;
  const int m0 = blockIdx.y * 32;
  const int w0 = blockIdx.x * 32;
  const float* xb = X + (bl * 4096 + m0) * 128 + w0;
  int row = tid >> 3, cg = tid & 7;
  float4 v = *(const float4*)(xb + (long)row * 128 + cg * 4);
  tile[row][cg * 4 + 0] = v.x;
  tile[row][cg * 4 + 1] = v.y;
  tile[row][cg * 4 + 2] = v.z;
  tile[row][cg * 4 + 3] = v.w;
  __syncthreads();
  if (tid < 128) {
    int wv = tid & 31, mg = tid >> 5;          // out row wv, 8 m's per thread
    float t[8];
#pragma unroll
    for (int i = 0; i < 8; ++i) t[i] = tile[mg * 8 + i][wv];
    unsigned word = PKFP4(0u, t[0], t[1], 0);
    word = PKFP4(word, t[2], t[3], 1);
    word = PKFP4(word, t[4], t[5], 2);
    word = PKFP4(word, t[6], t[7], 3);
    long r = bl * 128 + w0 + wv;
    long k = m0 + mg * 8;
    *(int*)(out4 + tile4_addr(r, k, 64)) = (int)word;
  }
}

// -------- W1T8 = fp8-tiled (W1*16) [256f][128w]; W2T8 = fp8-tiled (W2*16) [128cc][256f] --------
__global__ __launch_bounds__(256) void prep_params(const float* __restrict__ W1,
                                                   const float* __restrict__ W2,
                                                   unsigned char* __restrict__ W1T8,
                                                   unsigned char* __restrict__ W2T8) {
  int idx = blockIdx.x * 256 + threadIdx.x;          // 0..65535
  if (idx < 32768) {
    int f = idx >> 7, wv = idx & 127;
    float v = W1[wv * 256 + f] * 16.0f;              // W1 is [128w][256f]
    int pk = __builtin_amdgcn_cvt_pk_fp8_f32(v, v, 0, 0);
    W1T8[tiled_addr(f, wv, 2)] = (unsigned char)(pk & 0xff);
  } else {
    int t = idx - 32768;
    int cc = t >> 8, f = t & 255;
    float v = W2[f * 128 + cc] * 16.0f;              // W2 is [256f][128c]
    int pk = __builtin_amdgcn_cvt_pk_fp8_f32(v, v, 0, 0);
    W2T8[tiled_addr(cc, f, 4)] = (unsigned char)(pk & 0xff);
  }
}

// ------- gemmS1 v5 (r3-proven, 97.6 us, session-best): LDS-ring main loop
// (3 slots x 16KB, slot = 2 kt), counted vmcnt, coarse body; swapped-operand
// MFMA (acc lanes = n, regs = w, scale_b=124 folds /8); fused epilogue
// S1'->mini1->mini2->fp4 pack. -------
__global__ __launch_bounds__(256, 3) void gemmS1(const unsigned char* __restrict__ A4,
                                                 const unsigned char* __restrict__ X4,
                                                 const unsigned char* __restrict__ W1T8,
                                                 const unsigned char* __restrict__ W2T8,
                                                 unsigned char* __restrict__ t2T4,
                                                 const float* __restrict__ b1,
                                                 int K, int gx) {
  __shared__ unsigned char lds[49152];         // ring 3x16KB; later S1buf[16K]+hbuf[32K]
  const int tid = threadIdx.x;
  const int l = tid & 63;
  const int w = tid >> 6;                      // 0..3
  long g = remap_wg(blockIdx.x, gridDim.x, gx);   // gx = 32
  const long row0 = (g % gx) * 128;
  const long bl = g / gx;
  const int nkb = K >> 6;
  const int wr = w >> 1, wc = w & 1;
  const unsigned char* sAp = A4 + (((row0 >> 5) + w) * (long)nkb) * 1024 + l * 16;
  const unsigned char* sXp = X4 + ((bl * 4 + w) * (long)nkb) * 1024 + l * 16;
  unsigned char* ldsw = lds + w * 1024;        // stage dest base within slot
  const unsigned char* rA = lds + (wr * 2) * 1024 + l * 16;
  const unsigned char* rX = lds + 4096 + (wc * 2) * 1024 + l * 16;

  f32x16 acc[2][2] = {};
  opnd aE[2], xE[2], aO[2], xO[2];             // even/odd kt frag sets
  const i32x4 z4 = {0, 0, 0, 0};
#pragma unroll
  for (int fi = 0; fi < 2; ++fi) {
    aE[fi].v4[1] = z4; xE[fi].v4[1] = z4;
    aO[fi].v4[1] = z4; xO[fi].v4[1] = z4;
  }

#define STG(B, SL) do { long o0_ = (long)(2 * (B)) * 1024; long o1_ = o0_ + 1024;     \
    unsigned char* d_ = ldsw + (SL) * 16384;                                          \
    __builtin_amdgcn_global_load_lds((const unsigned int*)(const void*)(sAp + o0_),   \
                                     (unsigned int*)(d_), 16, 0, 0);                  \
    __builtin_amdgcn_global_load_lds((const unsigned int*)(const void*)(sXp + o0_),   \
                                     (unsigned int*)(d_ + 4096), 16, 0, 0);           \
    __builtin_amdgcn_global_load_lds((const unsigned int*)(const void*)(sAp + o1_),   \
                                     (unsigned int*)(d_ + 8192), 16, 0, 0);           \
    __builtin_amdgcn_global_load_lds((const unsigned int*)(const void*)(sXp + o1_),   \
                                     (unsigned int*)(d_ + 12288), 16, 0, 0);          \
  } while (0)
#define LDF(SL, HALF, AV, XV) do { const long s_ = (SL) * 16384 + (HALF) * 8192;      \
    AV[0].v4[0] = *(const i32x4*)(rA + s_);                                           \
    AV[1].v4[0] = *(const i32x4*)(rA + s_ + 1024);                                    \
    XV[0].v4[0] = *(const i32x4*)(rX + s_);                                           \
    XV[1].v4[0] = *(const i32x4*)(rX + s_ + 1024); } while (0)
#define MFMAS(AV, XV) do {                                                            \
    __builtin_amdgcn_s_setprio(1);                                                    \
    _Pragma("unroll") for (int fi = 0; fi < 2; ++fi)                                  \
      _Pragma("unroll") for (int j = 0; j < 2; ++j)                                   \
        acc[fi][j] = __builtin_amdgcn_mfma_scale_f32_32x32x64_f8f6f4(                 \
            XV[j].v8, AV[fi].v8, acc[fi][j], 4, 4, 0, 127, 0, 124);                   \
    __builtin_amdgcn_s_setprio(0); } while (0)
#define BODYS(SL, SS, DOSTG, B, N) do {                                               \
    LDF(SL, 0, aE, xE);                                                               \
    if (DOSTG) STG((B) + 2, SS);                                                      \
    LDF(SL, 1, aO, xO);                                                               \
    MFMAS(aE, xE);                                                                    \
    MFMAS(aO, xO);                                                                    \
    asm volatile("s_waitcnt vmcnt(" N ")" ::: "memory");                              \
    __builtin_amdgcn_s_barrier(); } while (0)

  // nkt = 64 -> 32 bodies of 2 kt. Stages: body b stages S(b+2); last = S(31)@b29.
  STG(0, 0); STG(1, 1);
  asm volatile("s_waitcnt vmcnt(4)" ::: "memory");   // force S(0) complete
  __builtin_amdgcn_s_barrier();
  for (int b = 0; b < 30; b += 3) {
    BODYS(0, 2, 1, b + 0, "4");
    BODYS(1, 0, 1, b + 1, "4");
    BODYS(2, 1, 1, b + 2, "4");
  }
  BODYS(0, 0, 0, 30, "0");
  BODYS(1, 0, 0, 31, "0");
#undef STG
#undef LDF
#undef MFMAS
#undef BODYS

  unsigned char* S1buf = lds;                  // 16KB, aliases ring (dead now)
  unsigned char* hbuf = lds + 16384;           // 32KB

  // S1' = fp8(acc) -> S1buf (acc already carries the 2^-3 scale).
  const int hi = l >> 5;
  const int ln = l & 31;
#pragma unroll
  for (int fi = 0; fi < 2; ++fi) {
    int n = (wr * 2 + fi) * 32 + ln;
#pragma unroll
    for (int j = 0; j < 2; ++j) {
      int wb = (wc * 2 + j) * 32 + 4 * hi;
#pragma unroll
      for (int r4 = 0; r4 < 4; ++r4) {
        int w0 = wb + 8 * r4;
        int word = __builtin_amdgcn_cvt_pk_fp8_f32(acc[fi][j][4 * r4 + 0],
                                                   acc[fi][j][4 * r4 + 1], 0, false);
        word = __builtin_amdgcn_cvt_pk_fp8_f32(acc[fi][j][4 * r4 + 2],
                                               acc[fi][j][4 * r4 + 3], word, true);
        *(int*)(S1buf + tiled_addr(n, w0, 2)) = word;
      }
    }
  }
  __syncthreads();                             // acc dead; regs reused below

  // mini1 (swapped): acc = W1frag @ S1frag -> lanes = n, regs = f.
  const float c1 = 128.0f / 49152.0f;
#pragma unroll
  for (int hh = 0; hh < 2; ++hh) {
#pragma unroll
    for (int fi = 0; fi < 2; ++fi)
#pragma unroll
      for (int jb = 0; jb < 2; ++jb) acc[fi][jb] = (f32x16){};
#pragma unroll
    for (int kt1 = 0; kt1 < 2; ++kt1) {
#pragma unroll
      for (int jb = 0; jb < 2; ++jb) {
        opnd aw;
        const unsigned char* pW = W1T8 + (long)((hh * 4 + wc * 2 + jb) * 2 + kt1) * 2048 + l * 16;
        aw.v4[0] = *(const i32x4*)(pW);
        aw.v4[1] = *(const i32x4*)(pW + 1024);
#pragma unroll
        for (int fi = 0; fi < 2; ++fi) {
          opnd bs;
          const unsigned char* pS = S1buf + (long)((wr * 2 + fi) * 2 + kt1) * 2048 + l * 16;
          bs.v4[0] = *(const i32x4*)(pS);
          bs.v4[1] = *(const i32x4*)(pS + 1024);
          acc[fi][jb] = __builtin_amdgcn_mfma_scale_f32_32x32x64_f8f6f4(
              aw.v8, bs.v8, acc[fi][jb], 0, 0, 0, 127, 0, 127);
        }
      }
    }
#pragma unroll
    for (int jb = 0; jb < 2; ++jb) {
      int fb = (hh * 4 + wc * 2 + jb) * 32 + 4 * hi;
#pragma unroll
      for (int r4 = 0; r4 < 4; ++r4) {
        int f0 = fb + 8 * r4;
        float4 bb = *(const float4*)(b1 + f0);
#pragma unroll
        for (int fi = 0; fi < 2; ++fi) {
          int n = (wr * 2 + fi) * 32 + ln;
          float v0 = fmaxf(fmaf(acc[fi][jb][4 * r4 + 0], c1, bb.x * 128.0f), 0.0f);
          float v1 = fmaxf(fmaf(acc[fi][jb][4 * r4 + 1], c1, bb.y * 128.0f), 0.0f);
          float v2 = fmaxf(fmaf(acc[fi][jb][4 * r4 + 2], c1, bb.z * 128.0f), 0.0f);
          float v3 = fmaxf(fmaf(acc[fi][jb][4 * r4 + 3], c1, bb.w * 128.0f), 0.0f);
          int word = __builtin_amdgcn_cvt_pk_fp8_f32(v0, v1, 0, false);
          word = __builtin_amdgcn_cvt_pk_fp8_f32(v2, v3, word, true);
          *(int*)(hbuf + tiled_addr(n, f0, 4)) = word;
        }
      }
    }
  }
  __syncthreads();                             // hbuf complete

  // mini2 (unswapped; lane = cc matches t2T4 store): acc = h' @ W2T8^T over 256 f.
#pragma unroll
  for (int fi = 0; fi < 2; ++fi)
#pragma unroll
    for (int jb = 0; jb < 2; ++jb) acc[fi][jb] = (f32x16){};
#pragma unroll
  for (int kt2 = 0; kt2 < 4; ++kt2) {
#pragma unroll
    for (int jb = 0; jb < 2; ++jb) {
      opnd bw;
      const unsigned char* pW = W2T8 + (long)((wc * 2 + jb) * 4 + kt2) * 2048 + l * 16;
      bw.v4[0] = *(const i32x4*)(pW);
      bw.v4[1] = *(const i32x4*)(pW + 1024);
#pragma unroll
      for (int fi = 0; fi < 2; ++fi) {
        opnd ah;
        const unsigned char* pH = hbuf + (long)((wr * 2 + fi) * 4 + kt2) * 2048 + l * 16;
        ah.v4[0] = *(const i32x4*)(pH);
        ah.v4[1] = *(const i32x4*)(pH + 1024);
        acc[fi][jb] = __builtin_amdgcn_mfma_scale_f32_32x32x64_f8f6f4(
            ah.v8, bw.v8, acc[fi][jb], 0, 0, 0, 127, 0, 127);
      }
    }
  }
  unsigned char* ob = t2T4 + bl * 262144;
#pragma unroll
  for (int fi = 0; fi < 2; ++fi) {
#pragma unroll
    for (int jb = 0; jb < 2; ++jb) {
      int cc = wc * 64 + jb * 32 + ln;
#pragma unroll
      for (int run = 0; run < 4; ++run) {
        long n0 = row0 + wr * 64 + fi * 32 + 8 * run + 4 * hi;
        const float s = 0.125f;                // 256 / 2048
        unsigned pkw = PKFP4(0u, acc[fi][jb][run * 4 + 0] * s,
                                 acc[fi][jb][run * 4 + 1] * s, 0);
        pkw = PKFP4(pkw, acc[fi][jb][run * 4 + 2] * s,
                         acc[fi][jb][run * 4 + 3] * s, 1);
        *(ushort*)(ob + tile4_addr(cc, n0, 64)) = (ushort)pkw;
      }
    }
  }
}

// ------- G4+lsm v2 (r3-proven, best-total config): 8-wave MX-fp4 GEMM, fused
// log_softmax. Ring 8 slots x 8KB (64KB LDS), A direct prefetch dist-3 (4 reg
// sets), B staged 6 ahead; steady-state vmcnt(10); 8r x 8c per-XCD remap. -------
__global__ __launch_bounds__(512) void gemm256sm(const unsigned char* __restrict__ A4,
                                                 const unsigned char* __restrict__ B4,
                                                 float* __restrict__ out,
                                                 const float* __restrict__ bias,
                                                 float ooScale, int K, int gx,
                                                 int chunkBase) {
  __shared__ unsigned char ring[65536];        // 8 slots x 8KB (B stage)
  const int tid = threadIdx.x;
  const int l = tid & 63;
  const int w = tid >> 6;
  int lin = blockIdx.x;
  const int nwg = gridDim.x;
  if (gx == 16 && (nwg & 63) == 0) {
    // 8r x (nwg/64)c per XCD: halves the per-XCD adj footprint vs plain swizzle.
    int xcd = lin & 7, idx = lin >> 3;
    int cpg = nwg >> 6;
    int r = ((xcd & 1) << 3) + (idx & 7);
    int c = (xcd >> 1) * cpg + (idx >> 3);
    lin = c * gx + r;
  } else if ((nwg & 7) == 0) {
    int cpx = nwg >> 3;
    lin = (lin & 7) * cpx + (lin >> 3);
  }
  const long row0 = (long)(lin % gx) * 256;
  const long col0 = (long)(lin / gx) * 256;
  const int nkb = K >> 6;
  const unsigned char* sBp = B4 + (((col0 >> 5) + w) * (long)nkb) * 1024 + l * 16;
  unsigned char* ringw = ring + w * 1024;
  const unsigned char* ringr = ring + ((w & 1) * 4) * 1024 + l * 16;
  const unsigned char* pA = A4 + (((row0 + (w >> 1) * 64) >> 5) * (long)nkb) * 1024 + l * 16;

  f32x16 acc[2][4] = {};
  opnd bv[4], a0v[2], a1v[2], a2v[2], a3v[2];
  const i32x4 z4 = {0, 0, 0, 0};
#pragma unroll
  for (int j = 0; j < 4; ++j) bv[j].v4[1] = z4;
#pragma unroll
  for (int fi = 0; fi < 2; ++fi) {
    a0v[fi].v4[1] = z4; a1v[fi].v4[1] = z4; a2v[fi].v4[1] = z4; a3v[fi].v4[1] = z4;
  }

#define STGB(KT) __builtin_amdgcn_global_load_lds(                                    \
    (const unsigned int*)(const void*)(sBp + (long)(KT) * 1024),                      \
    (unsigned int*)(ringw + (((KT) & 7) << 13)), 16, 0, 0)
#define LOADA(KT, AV) do { long o_ = (long)(KT) * 1024;                               \
    AV[0].v4[0] = *(const i32x4*)(pA + o_);                                           \
    AV[1].v4[0] = *(const i32x4*)(pA + (long)nkb * 1024 + o_); } while (0)
#define LDB(KT) do { const unsigned char* p_ = ringr + (((KT) & 7) << 13);            \
    bv[0].v4[0] = *(const i32x4*)(p_);                                                \
    bv[1].v4[0] = *(const i32x4*)(p_ + 1024);                                         \
    bv[2].v4[0] = *(const i32x4*)(p_ + 2048);                                         \
    bv[3].v4[0] = *(const i32x4*)(p_ + 3072); } while (0)
#define MFMAS(AV) do { __builtin_amdgcn_s_setprio(1);                                 \
    _Pragma("unroll") for (int fi = 0; fi < 2; ++fi)                                  \
      _Pragma("unroll") for (int j = 0; j < 4; ++j)                                   \
        acc[fi][j] = __builtin_amdgcn_mfma_scale_f32_32x32x64_f8f6f4(                 \
            AV[fi].v8, bv[j].v8, acc[fi][j], 4, 4, 0, 127, 0, 127);                   \
    __builtin_amdgcn_s_setprio(0); } while (0)
// Body KT: ds-read slot KT, issue A(KT+3), stage slot KT+6, wait, 8 MFMA, barrier.
#define BODY(KT, N, DOSTG, DOA, ALD, AUSE) do {                                       \
    LDB(KT);                                                                          \
    if (DOA) LOADA((KT) + 3, ALD);                                                    \
    if (DOSTG) STGB((KT) + 6);                                                        \
    asm volatile("s_waitcnt vmcnt(" N ")" ::: "memory");                              \
    MFMAS(AUSE);                                                                      \
    __builtin_amdgcn_s_barrier(); } while (0)

  const int nkt = K >> 6;                      // 64
  LOADA(0, a0v); LOADA(1, a1v); LOADA(2, a2v);
  STGB(0); STGB(1); STGB(2); STGB(3); STGB(4); STGB(5);
  asm volatile("s_waitcnt vmcnt(5)" ::: "memory");   // own S(0) done (A(0..2) older)
  __builtin_amdgcn_s_barrier();

  BODY(0, "7", 1, 1, a3v, a0v);
  BODY(1, "9", 1, 1, a0v, a1v);
  BODY(2, "11", 1, 1, a1v, a2v);
  for (int kt = 3; kt + 9 <= nkt - 1; kt += 4) {     // kt = 3..51, bodies 3..54
    BODY(kt,     "10", 1, 1, a2v, a3v);
    BODY(kt + 1, "10", 1, 1, a3v, a0v);
    BODY(kt + 2, "10", 1, 1, a0v, a1v);
    BODY(kt + 3, "10", 1, 1, a1v, a2v);
  }
  BODY(55, "10", 1, 1, a2v, a3v);
  BODY(56, "10", 1, 1, a3v, a0v);
  BODY(57, "10", 1, 1, a0v, a1v);                    // stages S(63), last
  BODY(58, "9",  0, 1, a1v, a2v);
  BODY(59, "8",  0, 1, a2v, a3v);
  BODY(60, "7",  0, 1, a3v, a0v);
  BODY(61, "4",  0, 0, a0v, a1v);
  BODY(62, "2",  0, 0, a0v, a2v);
  BODY(63, "0",  0, 0, a0v, a3v);
#undef STGB
#undef LOADA
#undef LDB
#undef MFMAS
#undef BODY

  const int hi = l >> 5;
  const int bl = (int)(col0 >> 7) + (w & 1);
  float bb[4];
#pragma unroll
  for (int j = 0; j < 4; ++j) bb[j] = bias[j * 32 + (l & 31)];
#pragma unroll
  for (int fi = 0; fi < 2; ++fi) {
#pragma unroll
    for (int rr = 0; rr < 16; ++rr) {
      float v0 = acc[fi][0][rr] * ooScale + bb[0];
      float v1 = acc[fi][1][rr] * ooScale + bb[1];
      float v2 = acc[fi][2][rr] * ooScale + bb[2];
      float v3 = acc[fi][3][rr] * ooScale + bb[3];
      float m = fmaxf(fmaxf(v0, v1), fmaxf(v2, v3));
#pragma unroll
      for (int o = 16; o > 0; o >>= 1) m = fmaxf(m, __shfl_xor(m, o));
      float s = __expf(v0 - m) + __expf(v1 - m) + __expf(v2 - m) + __expf(v3 - m);
#pragma unroll
      for (int o = 16; o > 0; o >>= 1) s += __shfl_xor(s, o);
      float lse = m + __logf(s);
      long row = row0 + (w >> 1) * 64 + fi * 32 + ((rr & 3) + 8 * (rr >> 2) + 4 * hi);
      float* dst = out + ((long)(chunkBase + bl) * 4096 + row) * 128;
      dst[(l & 31)] = v0 - lse;
      dst[32 + (l & 31)] = v1 - lse;
      dst[64 + (l & 31)] = v2 - lse;
      dst[96 + (l & 31)] = v3 - lse;
    }
  }
}

extern "C" void kernel_launch(void* const* d_in, const int* in_sizes, int n_in,
                              void* d_out, int out_size, void* d_ws, size_t ws_size,
                              hipStream_t stream) {
  const float* x = (const float*)d_in[0];    // [64][4096][128]
  const float* adj = (const float*)d_in[1];  // [4096][4096]
  const float* W1 = (const float*)d_in[2];   // [128][256]
  const float* b1 = (const float*)d_in[3];   // [256]
  const float* W2 = (const float*)d_in[4];   // [256][128]
  const float* b2 = (const float*)d_in[5];   // [128]
  float* out = (float*)d_out;
  char* ws = (char*)d_ws;

  unsigned char* adj4 = (unsigned char*)ws;                       // 8 MiB
  unsigned char* W1T8 = (unsigned char*)(ws + 8388608);           // 32 KiB
  unsigned char* W2T8 = (unsigned char*)(ws + 8388608 + 32768);   // 32 KiB
  const size_t base = 9ull * 1024 * 1024;

  // chunk c (even divisors of 64): need = base + 2 * c * 256KB (x4T + t2T4)
  const int cands[6] = {64, 32, 16, 8, 4, 2};
  int c = 2;
  for (int t = 0; t < 6; ++t) {
    size_t need = base + (size_t)cands[t] * 524288;
    if (need <= ws_size) { c = cands[t]; break; }
  }
  unsigned char* x4T = (unsigned char*)(ws + base);               // c * 256 KiB
  unsigned char* t2T4 = x4T + (size_t)c * 262144;                 // c * 256 KiB

  cvtAdj4t<<<8192, 256, 0, stream>>>(adj, adj4, (long)4096 * 4096);
  prep_params<<<256, 256, 0, stream>>>(W1, W2, W1T8, W2T8);

  int chunks = 64 / c;
  for (int cb = 0; cb < chunks; ++cb) {
    int base_bl = cb * c;
    const float* xc = x + (long)base_bl * 4096 * 128;

    // x -> fp4-tiled transpose (rows = bl*128 + w, k = m)
    cvtX4t<<<dim3(4, 128, c), 256, 0, stream>>>(xc, x4T);
    // gemmS1 v5: t2T4 = fp4(256 * (relu((adj@x)@W1 + b1) @ W2)), K = 4096
    gemmS1<<<32 * c, 256, 0, stream>>>(adj4, x4T, W1T8, W2T8, t2T4, b1, 4096, 32);
    // G4+lsm v2: out = log_softmax(adj@t2 + b2)
    gemm256sm<<<16 * (c / 2), 512, 0, stream>>>(adj4, t2T4, out, b2,
                                                1.0f / 6291456.0f, 4096, 16, base_bl);
  }
}